// Round 10
// baseline (311.699 us; speedup 1.0000x reference)
//
#include <hip/hip_runtime.h>
#include <math.h>

#define N_NODES 50000
#define N_EDGES 800000
#define N_EVAL  500000
#define CSTRIDE 16                          // 1 deg counter per 64B line (build)
#define MAXDEG  64                          // bucket capacity (max observed deg ~35)
#define NB_GEMM ((N_NODES + 63) / 64)       // 782
#define NCHUNK  (N_NODES * 24)              // 1200000 (v,c) chunks
#define NB_AGG  ((NCHUNK + 255) / 256)      // 4688 (single-chunk aggr1)
#define NSLOT_C 1173                        // aggr slots in fusedC (391*3)
#define QEVAL   (N_EVAL / 4)                // 125000

__device__ __forceinline__ float4 f4add(float4 a, float4 b) {
    return make_float4(a.x + b.x, a.y + b.y, a.z + b.z, a.w + b.w);
}
__device__ __forceinline__ float4 f4fma(float s, float4 w, float4 a) {
    return make_float4(fmaf(s, w.x, a.x), fmaf(s, w.y, a.y),
                       fmaf(s, w.z, a.z), fmaf(s, w.w, a.w));
}
__device__ __forceinline__ float4 ld4(const float* p) {
    return *(const float4*)p;
}
// R7/R8 lessons: no NT stores; never cap VGPR below ~64 for gather bodies
// ((256,8) -> VGPR 32 -> scratch spill -> 218MB phantom writes).

// ---------------- role bodies ----------------

// bucket build: uint16 entries (node ids < 65536). R5-R9-verified correct.
__device__ __forceinline__ void bucket_role(int idx, const int* __restrict__ src,
                                            const int* __restrict__ dst,
                                            int* __restrict__ degS,
                                            unsigned short* __restrict__ bucket) {
    int t = idx * 256 + threadIdx.x;
    if (t < N_EDGES / 4) {
        int4 s = ((const int4*)src)[t];
        int4 d = ((const int4*)dst)[t];
        int r0 = atomicAdd(&degS[(size_t)d.x * CSTRIDE], 1);
        int r1 = atomicAdd(&degS[(size_t)d.y * CSTRIDE], 1);
        int r2 = atomicAdd(&degS[(size_t)d.z * CSTRIDE], 1);
        int r3 = atomicAdd(&degS[(size_t)d.w * CSTRIDE], 1);
        if (r0 < MAXDEG) bucket[(size_t)d.x * MAXDEG + r0] = (unsigned short)s.x;
        if (r1 < MAXDEG) bucket[(size_t)d.y * MAXDEG + r1] = (unsigned short)s.y;
        if (r2 < MAXDEG) bucket[(size_t)d.z * MAXDEG + r2] = (unsigned short)s.z;
        if (r3 < MAXDEG) bucket[(size_t)d.w * MAXDEG + r3] = (unsigned short)s.w;
    }
}

// index-line state for one node: deg + all 32 packed uint16 indices (one 64B line)
struct IdxL { int4 p0, p1, p2, p3; int deg; };

__device__ __forceinline__ IdxL idx_load(int v, const int* __restrict__ degS,
                                         const unsigned short* __restrict__ bucket) {
    IdxL L;
    const int4* bk4 = (const int4*)(bucket + (size_t)v * MAXDEG);
    L.deg = degS[(size_t)v * CSTRIDE];
    L.p0 = bk4[0]; L.p1 = bk4[1]; L.p2 = bk4[2]; L.p3 = bk4[3];
    return L;
}

// R2/R6-proven tiered gather using a preloaded index line.
__device__ __forceinline__ float4 aggr_gather(IdxL L, int v, int c,
        const float* __restrict__ x, const unsigned short* __restrict__ bucket) {
    const float* xp = x + c * 4;
    int deg = L.deg;
    if (deg > MAXDEG) deg = MAXDEG;
    int idx[32];
    idx[0]  = L.p0.x & 0xffff; idx[1]  = (int)((unsigned)L.p0.x >> 16);
    idx[2]  = L.p0.y & 0xffff; idx[3]  = (int)((unsigned)L.p0.y >> 16);
    idx[4]  = L.p0.z & 0xffff; idx[5]  = (int)((unsigned)L.p0.z >> 16);
    idx[6]  = L.p0.w & 0xffff; idx[7]  = (int)((unsigned)L.p0.w >> 16);
    idx[8]  = L.p1.x & 0xffff; idx[9]  = (int)((unsigned)L.p1.x >> 16);
    idx[10] = L.p1.y & 0xffff; idx[11] = (int)((unsigned)L.p1.y >> 16);
    idx[12] = L.p1.z & 0xffff; idx[13] = (int)((unsigned)L.p1.z >> 16);
    idx[14] = L.p1.w & 0xffff; idx[15] = (int)((unsigned)L.p1.w >> 16);
    idx[16] = L.p2.x & 0xffff; idx[17] = (int)((unsigned)L.p2.x >> 16);
    idx[18] = L.p2.y & 0xffff; idx[19] = (int)((unsigned)L.p2.y >> 16);
    idx[20] = L.p2.z & 0xffff; idx[21] = (int)((unsigned)L.p2.z >> 16);
    idx[22] = L.p2.w & 0xffff; idx[23] = (int)((unsigned)L.p2.w >> 16);
    idx[24] = L.p3.x & 0xffff; idx[25] = (int)((unsigned)L.p3.x >> 16);
    idx[26] = L.p3.y & 0xffff; idx[27] = (int)((unsigned)L.p3.y >> 16);
    idx[28] = L.p3.z & 0xffff; idx[29] = (int)((unsigned)L.p3.z >> 16);
    idx[30] = L.p3.w & 0xffff; idx[31] = (int)((unsigned)L.p3.w >> 16);

    const float4 z = make_float4(0.f, 0.f, 0.f, 0.f);
    float4 t0, t1, t2, t3, t4, t5, t6, t7, t8, t9, t10, t11, t12, t13, t14, t15;
    if (deg >= 16) {
        t0  = ld4(xp + (size_t)idx[0]  * 96);
        t1  = ld4(xp + (size_t)idx[1]  * 96);
        t2  = ld4(xp + (size_t)idx[2]  * 96);
        t3  = ld4(xp + (size_t)idx[3]  * 96);
        t4  = ld4(xp + (size_t)idx[4]  * 96);
        t5  = ld4(xp + (size_t)idx[5]  * 96);
        t6  = ld4(xp + (size_t)idx[6]  * 96);
        t7  = ld4(xp + (size_t)idx[7]  * 96);
        t8  = ld4(xp + (size_t)idx[8]  * 96);
        t9  = ld4(xp + (size_t)idx[9]  * 96);
        t10 = ld4(xp + (size_t)idx[10] * 96);
        t11 = ld4(xp + (size_t)idx[11] * 96);
        t12 = ld4(xp + (size_t)idx[12] * 96);
        t13 = ld4(xp + (size_t)idx[13] * 96);
        t14 = ld4(xp + (size_t)idx[14] * 96);
        t15 = ld4(xp + (size_t)idx[15] * 96);
    } else if (deg >= 8) {
        t0 = ld4(xp + (size_t)idx[0] * 96);
        t1 = ld4(xp + (size_t)idx[1] * 96);
        t2 = ld4(xp + (size_t)idx[2] * 96);
        t3 = ld4(xp + (size_t)idx[3] * 96);
        t4 = ld4(xp + (size_t)idx[4] * 96);
        t5 = ld4(xp + (size_t)idx[5] * 96);
        t6 = ld4(xp + (size_t)idx[6] * 96);
        t7 = ld4(xp + (size_t)idx[7] * 96);
        t8 = z; t9 = z; t10 = z; t11 = z; t12 = z; t13 = z; t14 = z; t15 = z;
        if (deg > 8)  t8  = ld4(xp + (size_t)idx[8]  * 96);
        if (deg > 9)  t9  = ld4(xp + (size_t)idx[9]  * 96);
        if (deg > 10) t10 = ld4(xp + (size_t)idx[10] * 96);
        if (deg > 11) t11 = ld4(xp + (size_t)idx[11] * 96);
        if (deg > 12) t12 = ld4(xp + (size_t)idx[12] * 96);
        if (deg > 13) t13 = ld4(xp + (size_t)idx[13] * 96);
        if (deg > 14) t14 = ld4(xp + (size_t)idx[14] * 96);
    } else {
        t0 = z; t1 = z; t2 = z; t3 = z; t4 = z; t5 = z; t6 = z; t7 = z;
        t8 = z; t9 = z; t10 = z; t11 = z; t12 = z; t13 = z; t14 = z; t15 = z;
        if (deg > 0) t0 = ld4(xp + (size_t)idx[0] * 96);
        if (deg > 1) t1 = ld4(xp + (size_t)idx[1] * 96);
        if (deg > 2) t2 = ld4(xp + (size_t)idx[2] * 96);
        if (deg > 3) t3 = ld4(xp + (size_t)idx[3] * 96);
        if (deg > 4) t4 = ld4(xp + (size_t)idx[4] * 96);
        if (deg > 5) t5 = ld4(xp + (size_t)idx[5] * 96);
        if (deg > 6) t6 = ld4(xp + (size_t)idx[6] * 96);
    }
    float4 a0 = f4add(f4add(f4add(t0, t1), f4add(t2, t3)),
                      f4add(f4add(t4, t5), f4add(t6, t7)));
    float4 a1 = f4add(f4add(f4add(t8, t9), f4add(t10, t11)),
                      f4add(f4add(t12, t13), f4add(t14, t15)));
    if (deg > 16) {
        float4 u0, u1, u2, u3, u4, u5, u6, u7;
        u0 = ld4(xp + (size_t)idx[16] * 96);
        u1 = z; u2 = z; u3 = z; u4 = z; u5 = z; u6 = z; u7 = z;
        if (deg > 17) u1 = ld4(xp + (size_t)idx[17] * 96);
        if (deg > 18) u2 = ld4(xp + (size_t)idx[18] * 96);
        if (deg > 19) u3 = ld4(xp + (size_t)idx[19] * 96);
        if (deg > 20) u4 = ld4(xp + (size_t)idx[20] * 96);
        if (deg > 21) u5 = ld4(xp + (size_t)idx[21] * 96);
        if (deg > 22) u6 = ld4(xp + (size_t)idx[22] * 96);
        if (deg > 23) u7 = ld4(xp + (size_t)idx[23] * 96);
        a0 = f4add(a0, f4add(f4add(u0, u1), f4add(u2, u3)));
        a1 = f4add(a1, f4add(f4add(u4, u5), f4add(u6, u7)));
    }
    if (deg > 24) {
        float4 u0, u1, u2, u3, u4, u5, u6, u7;
        u0 = ld4(xp + (size_t)idx[24] * 96);
        u1 = z; u2 = z; u3 = z; u4 = z; u5 = z; u6 = z; u7 = z;
        if (deg > 25) u1 = ld4(xp + (size_t)idx[25] * 96);
        if (deg > 26) u2 = ld4(xp + (size_t)idx[26] * 96);
        if (deg > 27) u3 = ld4(xp + (size_t)idx[27] * 96);
        if (deg > 28) u4 = ld4(xp + (size_t)idx[28] * 96);
        if (deg > 29) u5 = ld4(xp + (size_t)idx[29] * 96);
        if (deg > 30) u6 = ld4(xp + (size_t)idx[30] * 96);
        if (deg > 31) u7 = ld4(xp + (size_t)idx[31] * 96);
        a0 = f4add(a0, f4add(f4add(u0, u1), f4add(u2, u3)));
        a1 = f4add(a1, f4add(f4add(u4, u5), f4add(u6, u7)));
    }
    if (deg > 32) {                          // ~1e-4 of nodes
        const unsigned short* bk = bucket + (size_t)v * MAXDEG;
        for (int i = 32; i < deg; ++i)
            a0 = f4add(a0, ld4(xp + (size_t)bk[i] * 96));
    }
    return f4add(a0, a1);
}

// single-chunk aggr role (R6-proven: 24 threads/node, 4 floats each)
__device__ __forceinline__ void aggr_role1(int slot, const float* __restrict__ x,
        const int* __restrict__ degS, const unsigned short* __restrict__ bucket,
        float* __restrict__ out) {
    int gt = slot * 256 + threadIdx.x;
    if (gt >= NCHUNK) return;
    int v = gt / 24;
    int c = gt - v * 24;
    IdxL L = idx_load(v, degS, bucket);
    float4 r = aggr_gather(L, v, c, x, bucket);
    *(float4*)(out + (size_t)v * 96 + c * 4) = r;
}

// 4-chunk pipelined aggr role (R9-proven inside fusedC): next chunk's index
// line issued before current chunk's gathers are consumed.
__device__ __forceinline__ void aggr_role4(int slot, int stride256,
        const float* __restrict__ x, const int* __restrict__ degS,
        const unsigned short* __restrict__ bucket, float* __restrict__ out) {
    const int STR = stride256 * 256;
    int gt = slot * 256 + threadIdx.x;
    bool val = gt < NCHUNK;
    int v = 0, c = 0;
    IdxL L;
    if (val) {
        v = gt / 24; c = gt - v * 24;
        L = idx_load(v, degS, bucket);
    }
    #pragma unroll
    for (int k = 0; k < 4; ++k) {
        int gtn = gt + STR;
        bool valn = (k < 3) && (gtn < NCHUNK);
        int vn = 0, cn = 0;
        IdxL Ln;
        if (valn) {
            vn = gtn / 24; cn = gtn - vn * 24;
            Ln = idx_load(vn, degS, bucket);
        }
        if (val) {
            float4 r = aggr_gather(L, v, c, x, bucket);
            *(float4*)(out + (size_t)v * 96 + c * 4) = r;
        }
        gt = gtn; v = vn; c = cn; L = Ln; val = valn;
    }
}

// Self GEMM, 32-row K-chunks (R2/R6-proven; used by k_fusedA). LDS 21KB.
__device__ __forceinline__ void selfgemm32(int g, const float* __restrict__ X,
                                           const float* __restrict__ W96,
                                           const float* __restrict__ bias,
                                           float* __restrict__ S,
                                           float* __restrict__ Ws,   // [32*96]
                                           float* __restrict__ xT) { // [32*68]
    const int tid = threadIdx.x;
    const int j   = tid & 31;
    const int ty  = tid >> 5;
    const int v0  = g * 64;

    float acc[8][3];
    float b0 = bias[j], b1 = bias[j + 32], b2 = bias[j + 64];
    #pragma unroll
    for (int r = 0; r < 8; ++r) { acc[r][0] = b0; acc[r][1] = b1; acc[r][2] = b2; }

    const int sr = tid >> 2;
    const int sc = tid & 3;
    int sv = v0 + sr; if (sv >= N_NODES) sv = N_NODES - 1;

    for (int kc = 0; kc < 3; ++kc) {
        const float* W = W96 + kc * (32 * 96);
        const int kbase = kc * 32;
        __syncthreads();
        #pragma unroll
        for (int i = 0; i < 3; ++i) {
            int f = tid + i * 256;
            *(float4*)(Ws + f * 4) = ld4(W + f * 4);
        }
        {
            const float* rowp = X + (size_t)sv * 96 + kbase;
            float4 a = ld4(rowp + sc * 4);
            float4 b = ld4(rowp + sc * 4 + 16);
            int k0 = sc * 4;
            xT[(k0 + 0) * 68 + sr] = a.x;
            xT[(k0 + 1) * 68 + sr] = a.y;
            xT[(k0 + 2) * 68 + sr] = a.z;
            xT[(k0 + 3) * 68 + sr] = a.w;
            xT[(k0 + 16) * 68 + sr] = b.x;
            xT[(k0 + 17) * 68 + sr] = b.y;
            xT[(k0 + 18) * 68 + sr] = b.z;
            xT[(k0 + 19) * 68 + sr] = b.w;
        }
        __syncthreads();
        #pragma unroll 8
        for (int kk = 0; kk < 32; ++kk) {
            float w0 = Ws[kk * 96 + j];
            float w1 = Ws[kk * 96 + j + 32];
            float w2 = Ws[kk * 96 + j + 64];
            float4 xa = *(const float4*)(xT + kk * 68 + ty * 8);
            float4 xb = *(const float4*)(xT + kk * 68 + ty * 8 + 4);
#define ROWFMA(r, xv)                                   \
            acc[r][0] = fmaf(xv, w0, acc[r][0]);        \
            acc[r][1] = fmaf(xv, w1, acc[r][1]);        \
            acc[r][2] = fmaf(xv, w2, acc[r][2]);
            ROWFMA(0, xa.x) ROWFMA(1, xa.y) ROWFMA(2, xa.z) ROWFMA(3, xa.w)
            ROWFMA(4, xb.x) ROWFMA(5, xb.y) ROWFMA(6, xb.z) ROWFMA(7, xb.w)
#undef ROWFMA
        }
    }
    #pragma unroll
    for (int r = 0; r < 8; ++r) {
        int v = v0 + ty * 8 + r;
        if (v < N_NODES) {
            S[(size_t)v * 96 + j]      = acc[r][0];
            S[(size_t)v * 96 + j + 32] = acc[r][1];
            S[(size_t)v * 96 + j + 64] = acc[r][2];
        }
    }
}

// Self GEMM, 16-row K-chunks (R9-proven; used by k_fusedC). LDS 10.75KB.
__device__ __forceinline__ void selfgemm16(int g, const float* __restrict__ X,
                                           const float* __restrict__ W96,
                                           const float* __restrict__ bias,
                                           float* __restrict__ S,
                                           float* __restrict__ Ws,   // [16*96]
                                           float* __restrict__ xT) { // [16*68]
    const int tid = threadIdx.x;
    const int j   = tid & 31;
    const int ty  = tid >> 5;
    const int v0  = g * 64;

    float acc[8][3];
    float b0 = bias[j], b1 = bias[j + 32], b2 = bias[j + 64];
    #pragma unroll
    for (int r = 0; r < 8; ++r) { acc[r][0] = b0; acc[r][1] = b1; acc[r][2] = b2; }

    const int sr = tid >> 2;
    const int sc = tid & 3;
    int sv = v0 + sr; if (sv >= N_NODES) sv = N_NODES - 1;

    for (int kc = 0; kc < 6; ++kc) {
        const float* W = W96 + kc * (16 * 96);
        const int kbase = kc * 16;
        __syncthreads();
        *(float4*)(Ws + tid * 4) = ld4(W + tid * 4);
        if (tid < 128)
            *(float4*)(Ws + (tid + 256) * 4) = ld4(W + (tid + 256) * 4);
        {
            float4 a = ld4(X + (size_t)sv * 96 + kbase + sc * 4);
            int k0 = sc * 4;
            xT[(k0 + 0) * 68 + sr] = a.x;
            xT[(k0 + 1) * 68 + sr] = a.y;
            xT[(k0 + 2) * 68 + sr] = a.z;
            xT[(k0 + 3) * 68 + sr] = a.w;
        }
        __syncthreads();
        #pragma unroll 8
        for (int kk = 0; kk < 16; ++kk) {
            float w0 = Ws[kk * 96 + j];
            float w1 = Ws[kk * 96 + j + 32];
            float w2 = Ws[kk * 96 + j + 64];
            float4 xa = *(const float4*)(xT + kk * 68 + ty * 8);
            float4 xb = *(const float4*)(xT + kk * 68 + ty * 8 + 4);
#define ROWFMA(r, xv)                                   \
            acc[r][0] = fmaf(xv, w0, acc[r][0]);        \
            acc[r][1] = fmaf(xv, w1, acc[r][1]);        \
            acc[r][2] = fmaf(xv, w2, acc[r][2]);
            ROWFMA(0, xa.x) ROWFMA(1, xa.y) ROWFMA(2, xa.z) ROWFMA(3, xa.w)
            ROWFMA(4, xb.x) ROWFMA(5, xb.y) ROWFMA(6, xb.z) ROWFMA(7, xb.w)
#undef ROWFMA
        }
    }
    #pragma unroll
    for (int r = 0; r < 8; ++r) {
        int v = v0 + ty * 8 + r;
        if (v < N_NODES) {
            S[(size_t)v * 96 + j]      = acc[r][0];
            S[(size_t)v * 96 + j + 32] = acc[r][1];
            S[(size_t)v * 96 + j + 64] = acc[r][2];
        }
    }
}

// ---------------- kernels ----------------

// A (R6-proven form): bucket build (even) || S1 = Features@W1r + b1 (odd)
__global__ __launch_bounds__(256) void k_fusedA(const int* __restrict__ src,
                                                const int* __restrict__ dst,
                                                int* __restrict__ degS,
                                                unsigned short* __restrict__ bucket,
                                                const float* __restrict__ X,
                                                const float* __restrict__ Wr,
                                                const float* __restrict__ bias,
                                                float* __restrict__ S) {
    __shared__ float Ws[32 * 96];
    __shared__ float xT[32 * 68];
    int b = blockIdx.x;
    if (b & 1) selfgemm32(b >> 1, X, Wr, bias, S, Ws, xT);
    else       bucket_role(b >> 1, src, dst, degS, bucket);
}

// pure aggregation layer 1 (R6-proven single-chunk form)
__global__ __launch_bounds__(256, 4) void k_aggr(const float* __restrict__ x,
                                                 const int* __restrict__ degS,
                                                 const unsigned short* __restrict__ bucket,
                                                 float* __restrict__ out) {
    aggr_role1(blockIdx.x, x, degS, bucket, out);
}

// C (R9-proven form): groups of 5 blocks: 2x selfgemm16(S2) + 3x 4-chunk aggr2.
__global__ __launch_bounds__(256, 4) void k_fusedC(const float* __restrict__ h1,
                                                   const int* __restrict__ degS,
                                                   const unsigned short* __restrict__ bucket,
                                                   float* __restrict__ aggrOut,
                                                   const float* __restrict__ Wr,
                                                   const float* __restrict__ bias,
                                                   float* __restrict__ S) {
    __shared__ float Ws[16 * 96];
    __shared__ float xT[16 * 68];
    int b = blockIdx.x;
    int g = b / 5, r = b - g * 5;
    if (r < 2) {
        int idx = g * 2 + r;                 // 0..781
        if (idx < NB_GEMM) selfgemm16(idx, h1, Wr, bias, S, Ws, xT);
    } else {
        int slot = g * 3 + (r - 2);          // 0..1172
        aggr_role4(slot, NSLOT_C, h1, degS, bucket, aggrOut);
    }
}

// Half GEMM: out = [RELU](P @ Wl + S). R4 192-thread static pipeline, 3 chunks.
template <int RELU>
__global__ __launch_bounds__(192) void k_gemmH(const float* __restrict__ P,
                                               const float* __restrict__ Wl,
                                               const float* __restrict__ S,
                                               float* __restrict__ out) {
    __shared__ float Ws[32 * 96];
    __shared__ float xT[32 * 68];
    const int tid = threadIdx.x;
    const int q   = tid % 24;
    const int rg  = tid / 24;
    const int v0  = blockIdx.x * 64;

    const int  row0 = tid >> 3,         qd0 = tid & 7;
    const int  row1 = (tid + 192) >> 3, qd1 = (tid + 192) & 7;
    const int  row2 = (tid + 384) >> 3, qd2 = (tid + 384) & 7;
    const bool has2 = (tid < 128);
    int sv0 = v0 + row0; if (sv0 >= N_NODES) sv0 = N_NODES - 1;
    int sv1 = v0 + row1; if (sv1 >= N_NODES) sv1 = N_NODES - 1;
    int sv2 = v0 + row2; if (sv2 >= N_NODES) sv2 = N_NODES - 1;

    float4 acc[8];
    #pragma unroll
    for (int r = 0; r < 8; ++r) acc[r] = make_float4(0.f, 0.f, 0.f, 0.f);

    float4 wreg0, wreg1, wreg2, wreg3;
    float4 xreg0, xreg1, xreg2;

    auto load_chunk = [&](int kc) {
        const float* W = Wl + kc * (32 * 96);
        const int kbase = kc * 32;
        wreg0 = *(const float4*)(W + (tid + 0 * 192) * 4);
        wreg1 = *(const float4*)(W + (tid + 1 * 192) * 4);
        wreg2 = *(const float4*)(W + (tid + 2 * 192) * 4);
        wreg3 = *(const float4*)(W + (tid + 3 * 192) * 4);
        xreg0 = *(const float4*)(P + (size_t)sv0 * 96 + kbase + qd0 * 4);
        xreg1 = *(const float4*)(P + (size_t)sv1 * 96 + kbase + qd1 * 4);
        if (has2) xreg2 = *(const float4*)(P + (size_t)sv2 * 96 + kbase + qd2 * 4);
    };
    auto store_chunk = [&]() {
        *(float4*)(Ws + (tid + 0 * 192) * 4) = wreg0;
        *(float4*)(Ws + (tid + 1 * 192) * 4) = wreg1;
        *(float4*)(Ws + (tid + 2 * 192) * 4) = wreg2;
        *(float4*)(Ws + (tid + 3 * 192) * 4) = wreg3;
        int k0 = qd0 * 4;
        xT[(k0 + 0) * 68 + row0] = xreg0.x;
        xT[(k0 + 1) * 68 + row0] = xreg0.y;
        xT[(k0 + 2) * 68 + row0] = xreg0.z;
        xT[(k0 + 3) * 68 + row0] = xreg0.w;
        int k1 = qd1 * 4;
        xT[(k1 + 0) * 68 + row1] = xreg1.x;
        xT[(k1 + 1) * 68 + row1] = xreg1.y;
        xT[(k1 + 2) * 68 + row1] = xreg1.z;
        xT[(k1 + 3) * 68 + row1] = xreg1.w;
        if (has2) {
            int k2 = qd2 * 4;
            xT[(k2 + 0) * 68 + row2] = xreg2.x;
            xT[(k2 + 1) * 68 + row2] = xreg2.y;
            xT[(k2 + 2) * 68 + row2] = xreg2.z;
            xT[(k2 + 3) * 68 + row2] = xreg2.w;
        }
    };

    load_chunk(0);
    for (int kc = 0; kc < 3; ++kc) {
        __syncthreads();
        store_chunk();
        if (kc < 2) load_chunk(kc + 1);
        __syncthreads();
        #pragma unroll 8
        for (int kk = 0; kk < 32; ++kk) {
            float4 w  = *(const float4*)(Ws + kk * 96 + q * 4);
            float4 xa = *(const float4*)(xT + kk * 68 + rg * 8);
            float4 xb = *(const float4*)(xT + kk * 68 + rg * 8 + 4);
            acc[0] = f4fma(xa.x, w, acc[0]);
            acc[1] = f4fma(xa.y, w, acc[1]);
            acc[2] = f4fma(xa.z, w, acc[2]);
            acc[3] = f4fma(xa.w, w, acc[3]);
            acc[4] = f4fma(xb.x, w, acc[4]);
            acc[5] = f4fma(xb.y, w, acc[5]);
            acc[6] = f4fma(xb.z, w, acc[6]);
            acc[7] = f4fma(xb.w, w, acc[7]);
        }
    }
    #pragma unroll
    for (int r = 0; r < 8; ++r) {
        int v = v0 + rg * 8 + r;
        if (v < N_NODES) {
            float4 s4 = *(const float4*)(S + (size_t)v * 96 + q * 4);
            float4 o = f4add(acc[r], s4);
            if (RELU) {
                o.x = fmaxf(o.x, 0.f); o.y = fmaxf(o.y, 0.f);
                o.z = fmaxf(o.z, 0.f); o.w = fmaxf(o.w, 0.f);
            }
            *(float4*)(out + (size_t)v * 96 + q * 4) = o;
        }
    }
}

// Edge scoring: sigmoid(dot(h[E0], h[E1])), 8 lanes/edge, 4 edges/thread
// (24 independent float4 gathers in flight; same MLP medicine as aggr).
__global__ __launch_bounds__(256) void k_score(const float* __restrict__ h,
                                               const int* __restrict__ E,
                                               float* __restrict__ out) {
    int t = blockIdx.x * 256 + threadIdx.x;
    int e = t >> 3, sub = t & 7;
    if (e >= QEVAL) return;
    int eA = e, eB = e + QEVAL, eC = e + 2 * QEVAL, eD = e + 3 * QEVAL;
    int sA = E[eA], sB = E[eB], sC = E[eC], sD = E[eD];
    int dA = E[N_EVAL + eA], dB = E[N_EVAL + eB];
    int dC = E[N_EVAL + eC], dD = E[N_EVAL + eD];
    const int off = sub * 12;
    const float* psA = h + (size_t)sA * 96 + off;
    const float* pdA = h + (size_t)dA * 96 + off;
    const float* psB = h + (size_t)sB * 96 + off;
    const float* pdB = h + (size_t)dB * 96 + off;
    const float* psC = h + (size_t)sC * 96 + off;
    const float* pdC = h + (size_t)dC * 96 + off;
    const float* psD = h + (size_t)sD * 96 + off;
    const float* pdD = h + (size_t)dD * 96 + off;
    float4 a0 = ld4(psA + 0), a1 = ld4(psA + 4), a2 = ld4(psA + 8);
    float4 b0 = ld4(pdA + 0), b1 = ld4(pdA + 4), b2 = ld4(pdA + 8);
    float4 c0 = ld4(psB + 0), c1 = ld4(psB + 4), c2 = ld4(psB + 8);
    float4 g0 = ld4(pdB + 0), g1 = ld4(pdB + 4), g2 = ld4(pdB + 8);
    float4 m0 = ld4(psC + 0), m1 = ld4(psC + 4), m2 = ld4(psC + 8);
    float4 n0 = ld4(pdC + 0), n1 = ld4(pdC + 4), n2 = ld4(pdC + 8);
    float4 u0 = ld4(psD + 0), u1 = ld4(psD + 4), u2 = ld4(psD + 8);
    float4 w0 = ld4(pdD + 0), w1 = ld4(pdD + 4), w2 = ld4(pdD + 8);
    float dotA = a0.x * b0.x + a0.y * b0.y + a0.z * b0.z + a0.w * b0.w
               + a1.x * b1.x + a1.y * b1.y + a1.z * b1.z + a1.w * b1.w
               + a2.x * b2.x + a2.y * b2.y + a2.z * b2.z + a2.w * b2.w;
    float dotB = c0.x * g0.x + c0.y * g0.y + c0.z * g0.z + c0.w * g0.w
               + c1.x * g1.x + c1.y * g1.y + c1.z * g1.z + c1.w * g1.w
               + c2.x * g2.x + c2.y * g2.y + c2.z * g2.z + c2.w * g2.w;
    float dotC = m0.x * n0.x + m0.y * n0.y + m0.z * n0.z + m0.w * n0.w
               + m1.x * n1.x + m1.y * n1.y + m1.z * n1.z + m1.w * n1.w
               + m2.x * n2.x + m2.y * n2.y + m2.z * n2.z + m2.w * n2.w;
    float dotD = u0.x * w0.x + u0.y * w0.y + u0.z * w0.z + u0.w * w0.w
               + u1.x * w1.x + u1.y * w1.y + u1.z * w1.z + u1.w * w1.w
               + u2.x * w2.x + u2.y * w2.y + u2.z * w2.z + u2.w * w2.w;
    dotA += __shfl_xor(dotA, 1, 64);
    dotB += __shfl_xor(dotB, 1, 64);
    dotC += __shfl_xor(dotC, 1, 64);
    dotD += __shfl_xor(dotD, 1, 64);
    dotA += __shfl_xor(dotA, 2, 64);
    dotB += __shfl_xor(dotB, 2, 64);
    dotC += __shfl_xor(dotC, 2, 64);
    dotD += __shfl_xor(dotD, 2, 64);
    dotA += __shfl_xor(dotA, 4, 64);
    dotB += __shfl_xor(dotB, 4, 64);
    dotC += __shfl_xor(dotC, 4, 64);
    dotD += __shfl_xor(dotD, 4, 64);
    if (sub == 0) {
        out[eA] = 1.f / (1.f + expf(-dotA));
        out[eB] = 1.f / (1.f + expf(-dotB));
        out[eC] = 1.f / (1.f + expf(-dotC));
        out[eD] = 1.f / (1.f + expf(-dotD));
    }
}

// ---------------- launch ----------------

extern "C" void kernel_launch(void* const* d_in, const int* in_sizes, int n_in,
                              void* d_out, int out_size, void* d_ws, size_t ws_size,
                              hipStream_t stream) {
    const float* Features = (const float*)d_in[0];
    const int*   A        = (const int*)d_in[1];   // [2, N_EDGES] int32
    const int*   E        = (const int*)d_in[2];   // [2, N_EVAL]
    const float* W1l = (const float*)d_in[3];
    const float* W1r = (const float*)d_in[4];
    const float* b1  = (const float*)d_in[5];
    const float* W2l = (const float*)d_in[6];
    const float* W2r = (const float*)d_in[7];
    const float* b2  = (const float*)d_in[8];
    float* out = (float*)d_out;

    char* p = (char*)d_ws;
    auto alloc = [&](size_t bytes) -> char* {
        char* q = p;
        p += (bytes + 255) & ~(size_t)255;
        return q;
    };
    int*   degS   = (int*)alloc((size_t)N_NODES * CSTRIDE * 4);   // 3.2 MB
    unsigned short* bucket =
        (unsigned short*)alloc((size_t)N_NODES * MAXDEG * 2);     // 6.4 MB
    float* bufA   = (float*)alloc((size_t)N_NODES * 96 * 4);      // aggr out / h2
    float* bufB   = (float*)alloc((size_t)N_NODES * 96 * 4);      // h1
    float* bufS   = (float*)alloc((size_t)N_NODES * 96 * 4);      // self term S1/S2

    const int* Asrc = A;
    const int* Adst = A + N_EDGES;

    hipMemsetAsync(degS, 0, (size_t)N_NODES * CSTRIDE * 4, stream);

    // bucket build || S1 = Features@W1r + b1  (independent, block-interleaved)
    k_fusedA<<<2 * NB_GEMM, 256, 0, stream>>>(Asrc, Adst, degS, bucket,
                                              Features, W1r, b1, bufS);
    // aggr1(Features) -> bufA  (single-chunk, R6-proven)
    k_aggr<<<NB_AGG, 256, 0, stream>>>(Features, degS, bucket, bufA);
    // h1 = relu(bufA@W1l + S1) -> bufB
    k_gemmH<1><<<NB_GEMM, 192, 0, stream>>>(bufA, W1l, bufS, bufB);
    // aggr2(h1) -> bufA || S2 = h1@W2r + b2 -> bufS  (R9-proven 5-block groups)
    k_fusedC<<<391 * 5, 256, 0, stream>>>(bufB, degS, bucket, bufA,
                                          W2r, b2, bufS);
    // h2 = bufA@W2l + S2 -> bufA
    k_gemmH<0><<<NB_GEMM, 192, 0, stream>>>(bufA, W2l, bufS, bufA);
    // score (4 edges/thread)
    k_score<<<(QEVAL * 8 + 255) / 256, 256, 0, stream>>>(bufA, E, out);
}

// Round 12
// 296.724 us; speedup vs baseline: 1.0505x; 1.0505x over previous
//
#include <hip/hip_runtime.h>
#include <math.h>

#define N_NODES 50000
#define N_EDGES 800000
#define N_EVAL  500000
#define CSTRIDE 16                          // 1 deg counter per 64B line (build)
#define MAXDEG  64                          // bucket capacity (max observed deg ~35)
#define NB_GEMM ((N_NODES + 63) / 64)       // 782
#define NCHUNK  (N_NODES * 24)              // 1200000 (v,c) chunks
#define NB_AGG  ((NCHUNK + 255) / 256)      // 4688 (single-chunk aggr1)
#define NSLOT_C 1173                        // aggr slots in fusedC (391*3)
#define HALF_EVAL (N_EVAL / 2)              // 250000

__device__ __forceinline__ float4 f4add(float4 a, float4 b) {
    return make_float4(a.x + b.x, a.y + b.y, a.z + b.z, a.w + b.w);
}
__device__ __forceinline__ float4 f4fma(float s, float4 w, float4 a) {
    return make_float4(fmaf(s, w.x, a.x), fmaf(s, w.y, a.y),
                       fmaf(s, w.z, a.z), fmaf(s, w.w, a.w));
}
__device__ __forceinline__ float4 ld4(const float* p) {
    return *(const float4*)p;
}
// Session lessons: no NT stores (R7); never cap VGPR below ~64 for gather
// bodies (R8: spill -> phantom HBM traffic); k_score MLP-deepening fails
// (R10: compiler serializes independent gathers, VGPR 36).

// ---------------- role bodies ----------------

// bucket build: uint16 entries (node ids < 65536). R5-R10-verified correct.
__device__ __forceinline__ void bucket_role(int idx, const int* __restrict__ src,
                                            const int* __restrict__ dst,
                                            int* __restrict__ degS,
                                            unsigned short* __restrict__ bucket) {
    int t = idx * 256 + threadIdx.x;
    if (t < N_EDGES / 4) {
        int4 s = ((const int4*)src)[t];
        int4 d = ((const int4*)dst)[t];
        int r0 = atomicAdd(&degS[(size_t)d.x * CSTRIDE], 1);
        int r1 = atomicAdd(&degS[(size_t)d.y * CSTRIDE], 1);
        int r2 = atomicAdd(&degS[(size_t)d.z * CSTRIDE], 1);
        int r3 = atomicAdd(&degS[(size_t)d.w * CSTRIDE], 1);
        if (r0 < MAXDEG) bucket[(size_t)d.x * MAXDEG + r0] = (unsigned short)s.x;
        if (r1 < MAXDEG) bucket[(size_t)d.y * MAXDEG + r1] = (unsigned short)s.y;
        if (r2 < MAXDEG) bucket[(size_t)d.z * MAXDEG + r2] = (unsigned short)s.z;
        if (r3 < MAXDEG) bucket[(size_t)d.w * MAXDEG + r3] = (unsigned short)s.w;
    }
}

// index-line state for one node: deg + all 32 packed uint16 indices (one 64B line)
struct IdxL { int4 p0, p1, p2, p3; int deg; };

__device__ __forceinline__ IdxL idx_load(int v, const int* __restrict__ degS,
                                         const unsigned short* __restrict__ bucket) {
    IdxL L;
    const int4* bk4 = (const int4*)(bucket + (size_t)v * MAXDEG);
    L.deg = degS[(size_t)v * CSTRIDE];
    L.p0 = bk4[0]; L.p1 = bk4[1]; L.p2 = bk4[2]; L.p3 = bk4[3];
    return L;
}

// R2/R6-proven tiered gather using a preloaded index line.
__device__ __forceinline__ float4 aggr_gather(IdxL L, int v, int c,
        const float* __restrict__ x, const unsigned short* __restrict__ bucket) {
    const float* xp = x + c * 4;
    int deg = L.deg;
    if (deg > MAXDEG) deg = MAXDEG;
    int idx[32];
    idx[0]  = L.p0.x & 0xffff; idx[1]  = (int)((unsigned)L.p0.x >> 16);
    idx[2]  = L.p0.y & 0xffff; idx[3]  = (int)((unsigned)L.p0.y >> 16);
    idx[4]  = L.p0.z & 0xffff; idx[5]  = (int)((unsigned)L.p0.z >> 16);
    idx[6]  = L.p0.w & 0xffff; idx[7]  = (int)((unsigned)L.p0.w >> 16);
    idx[8]  = L.p1.x & 0xffff; idx[9]  = (int)((unsigned)L.p1.x >> 16);
    idx[10] = L.p1.y & 0xffff; idx[11] = (int)((unsigned)L.p1.y >> 16);
    idx[12] = L.p1.z & 0xffff; idx[13] = (int)((unsigned)L.p1.z >> 16);
    idx[14] = L.p1.w & 0xffff; idx[15] = (int)((unsigned)L.p1.w >> 16);
    idx[16] = L.p2.x & 0xffff; idx[17] = (int)((unsigned)L.p2.x >> 16);
    idx[18] = L.p2.y & 0xffff; idx[19] = (int)((unsigned)L.p2.y >> 16);
    idx[20] = L.p2.z & 0xffff; idx[21] = (int)((unsigned)L.p2.z >> 16);
    idx[22] = L.p2.w & 0xffff; idx[23] = (int)((unsigned)L.p2.w >> 16);
    idx[24] = L.p3.x & 0xffff; idx[25] = (int)((unsigned)L.p3.x >> 16);
    idx[26] = L.p3.y & 0xffff; idx[27] = (int)((unsigned)L.p3.y >> 16);
    idx[28] = L.p3.z & 0xffff; idx[29] = (int)((unsigned)L.p3.z >> 16);
    idx[30] = L.p3.w & 0xffff; idx[31] = (int)((unsigned)L.p3.w >> 16);

    const float4 z = make_float4(0.f, 0.f, 0.f, 0.f);
    float4 t0, t1, t2, t3, t4, t5, t6, t7, t8, t9, t10, t11, t12, t13, t14, t15;
    if (deg >= 16) {
        t0  = ld4(xp + (size_t)idx[0]  * 96);
        t1  = ld4(xp + (size_t)idx[1]  * 96);
        t2  = ld4(xp + (size_t)idx[2]  * 96);
        t3  = ld4(xp + (size_t)idx[3]  * 96);
        t4  = ld4(xp + (size_t)idx[4]  * 96);
        t5  = ld4(xp + (size_t)idx[5]  * 96);
        t6  = ld4(xp + (size_t)idx[6]  * 96);
        t7  = ld4(xp + (size_t)idx[7]  * 96);
        t8  = ld4(xp + (size_t)idx[8]  * 96);
        t9  = ld4(xp + (size_t)idx[9]  * 96);
        t10 = ld4(xp + (size_t)idx[10] * 96);
        t11 = ld4(xp + (size_t)idx[11] * 96);
        t12 = ld4(xp + (size_t)idx[12] * 96);
        t13 = ld4(xp + (size_t)idx[13] * 96);
        t14 = ld4(xp + (size_t)idx[14] * 96);
        t15 = ld4(xp + (size_t)idx[15] * 96);
    } else if (deg >= 8) {
        t0 = ld4(xp + (size_t)idx[0] * 96);
        t1 = ld4(xp + (size_t)idx[1] * 96);
        t2 = ld4(xp + (size_t)idx[2] * 96);
        t3 = ld4(xp + (size_t)idx[3] * 96);
        t4 = ld4(xp + (size_t)idx[4] * 96);
        t5 = ld4(xp + (size_t)idx[5] * 96);
        t6 = ld4(xp + (size_t)idx[6] * 96);
        t7 = ld4(xp + (size_t)idx[7] * 96);
        t8 = z; t9 = z; t10 = z; t11 = z; t12 = z; t13 = z; t14 = z; t15 = z;
        if (deg > 8)  t8  = ld4(xp + (size_t)idx[8]  * 96);
        if (deg > 9)  t9  = ld4(xp + (size_t)idx[9]  * 96);
        if (deg > 10) t10 = ld4(xp + (size_t)idx[10] * 96);
        if (deg > 11) t11 = ld4(xp + (size_t)idx[11] * 96);
        if (deg > 12) t12 = ld4(xp + (size_t)idx[12] * 96);
        if (deg > 13) t13 = ld4(xp + (size_t)idx[13] * 96);
        if (deg > 14) t14 = ld4(xp + (size_t)idx[14] * 96);
    } else {
        t0 = z; t1 = z; t2 = z; t3 = z; t4 = z; t5 = z; t6 = z; t7 = z;
        t8 = z; t9 = z; t10 = z; t11 = z; t12 = z; t13 = z; t14 = z; t15 = z;
        if (deg > 0) t0 = ld4(xp + (size_t)idx[0] * 96);
        if (deg > 1) t1 = ld4(xp + (size_t)idx[1] * 96);
        if (deg > 2) t2 = ld4(xp + (size_t)idx[2] * 96);
        if (deg > 3) t3 = ld4(xp + (size_t)idx[3] * 96);
        if (deg > 4) t4 = ld4(xp + (size_t)idx[4] * 96);
        if (deg > 5) t5 = ld4(xp + (size_t)idx[5] * 96);
        if (deg > 6) t6 = ld4(xp + (size_t)idx[6] * 96);
    }
    float4 a0 = f4add(f4add(f4add(t0, t1), f4add(t2, t3)),
                      f4add(f4add(t4, t5), f4add(t6, t7)));
    float4 a1 = f4add(f4add(f4add(t8, t9), f4add(t10, t11)),
                      f4add(f4add(t12, t13), f4add(t14, t15)));
    if (deg > 16) {
        float4 u0, u1, u2, u3, u4, u5, u6, u7;
        u0 = ld4(xp + (size_t)idx[16] * 96);
        u1 = z; u2 = z; u3 = z; u4 = z; u5 = z; u6 = z; u7 = z;
        if (deg > 17) u1 = ld4(xp + (size_t)idx[17] * 96);
        if (deg > 18) u2 = ld4(xp + (size_t)idx[18] * 96);
        if (deg > 19) u3 = ld4(xp + (size_t)idx[19] * 96);
        if (deg > 20) u4 = ld4(xp + (size_t)idx[20] * 96);
        if (deg > 21) u5 = ld4(xp + (size_t)idx[21] * 96);
        if (deg > 22) u6 = ld4(xp + (size_t)idx[22] * 96);
        if (deg > 23) u7 = ld4(xp + (size_t)idx[23] * 96);
        a0 = f4add(a0, f4add(f4add(u0, u1), f4add(u2, u3)));
        a1 = f4add(a1, f4add(f4add(u4, u5), f4add(u6, u7)));
    }
    if (deg > 24) {
        float4 u0, u1, u2, u3, u4, u5, u6, u7;
        u0 = ld4(xp + (size_t)idx[24] * 96);
        u1 = z; u2 = z; u3 = z; u4 = z; u5 = z; u6 = z; u7 = z;
        if (deg > 25) u1 = ld4(xp + (size_t)idx[25] * 96);
        if (deg > 26) u2 = ld4(xp + (size_t)idx[26] * 96);
        if (deg > 27) u3 = ld4(xp + (size_t)idx[27] * 96);
        if (deg > 28) u4 = ld4(xp + (size_t)idx[28] * 96);
        if (deg > 29) u5 = ld4(xp + (size_t)idx[29] * 96);
        if (deg > 30) u6 = ld4(xp + (size_t)idx[30] * 96);
        if (deg > 31) u7 = ld4(xp + (size_t)idx[31] * 96);
        a0 = f4add(a0, f4add(f4add(u0, u1), f4add(u2, u3)));
        a1 = f4add(a1, f4add(f4add(u4, u5), f4add(u6, u7)));
    }
    if (deg > 32) {                          // ~1e-4 of nodes
        const unsigned short* bk = bucket + (size_t)v * MAXDEG;
        for (int i = 32; i < deg; ++i)
            a0 = f4add(a0, ld4(xp + (size_t)bk[i] * 96));
    }
    return f4add(a0, a1);
}

// single-chunk aggr role (R6-proven: 24 threads/node, 4 floats each)
__device__ __forceinline__ void aggr_role1(int slot, const float* __restrict__ x,
        const int* __restrict__ degS, const unsigned short* __restrict__ bucket,
        float* __restrict__ out) {
    int gt = slot * 256 + threadIdx.x;
    if (gt >= NCHUNK) return;
    int v = gt / 24;
    int c = gt - v * 24;
    IdxL L = idx_load(v, degS, bucket);
    float4 r = aggr_gather(L, v, c, x, bucket);
    *(float4*)(out + (size_t)v * 96 + c * 4) = r;
}

// 4-chunk pipelined aggr role (R9-proven inside fusedC): next chunk's index
// line issued before current chunk's gathers are consumed.
__device__ __forceinline__ void aggr_role4(int slot, int stride256,
        const float* __restrict__ x, const int* __restrict__ degS,
        const unsigned short* __restrict__ bucket, float* __restrict__ out) {
    const int STR = stride256 * 256;
    int gt = slot * 256 + threadIdx.x;
    bool val = gt < NCHUNK;
    int v = 0, c = 0;
    IdxL L;
    if (val) {
        v = gt / 24; c = gt - v * 24;
        L = idx_load(v, degS, bucket);
    }
    #pragma unroll
    for (int k = 0; k < 4; ++k) {
        int gtn = gt + STR;
        bool valn = (k < 3) && (gtn < NCHUNK);
        int vn = 0, cn = 0;
        IdxL Ln;
        if (valn) {
            vn = gtn / 24; cn = gtn - vn * 24;
            Ln = idx_load(vn, degS, bucket);
        }
        if (val) {
            float4 r = aggr_gather(L, v, c, x, bucket);
            *(float4*)(out + (size_t)v * 96 + c * 4) = r;
        }
        gt = gtn; v = vn; c = cn; L = Ln; val = valn;
    }
}

// Self GEMM, 32-row K-chunks (R2/R6-proven; used by k_fusedA). LDS 21KB.
__device__ __forceinline__ void selfgemm32(int g, const float* __restrict__ X,
                                           const float* __restrict__ W96,
                                           const float* __restrict__ bias,
                                           float* __restrict__ S,
                                           float* __restrict__ Ws,   // [32*96]
                                           float* __restrict__ xT) { // [32*68]
    const int tid = threadIdx.x;
    const int j   = tid & 31;
    const int ty  = tid >> 5;
    const int v0  = g * 64;

    float acc[8][3];
    float b0 = bias[j], b1 = bias[j + 32], b2 = bias[j + 64];
    #pragma unroll
    for (int r = 0; r < 8; ++r) { acc[r][0] = b0; acc[r][1] = b1; acc[r][2] = b2; }

    const int sr = tid >> 2;
    const int sc = tid & 3;
    int sv = v0 + sr; if (sv >= N_NODES) sv = N_NODES - 1;

    for (int kc = 0; kc < 3; ++kc) {
        const float* W = W96 + kc * (32 * 96);
        const int kbase = kc * 32;
        __syncthreads();
        #pragma unroll
        for (int i = 0; i < 3; ++i) {
            int f = tid + i * 256;
            *(float4*)(Ws + f * 4) = ld4(W + f * 4);
        }
        {
            const float* rowp = X + (size_t)sv * 96 + kbase;
            float4 a = ld4(rowp + sc * 4);
            float4 b = ld4(rowp + sc * 4 + 16);
            int k0 = sc * 4;
            xT[(k0 + 0) * 68 + sr] = a.x;
            xT[(k0 + 1) * 68 + sr] = a.y;
            xT[(k0 + 2) * 68 + sr] = a.z;
            xT[(k0 + 3) * 68 + sr] = a.w;
            xT[(k0 + 16) * 68 + sr] = b.x;
            xT[(k0 + 17) * 68 + sr] = b.y;
            xT[(k0 + 18) * 68 + sr] = b.z;
            xT[(k0 + 19) * 68 + sr] = b.w;
        }
        __syncthreads();
        #pragma unroll 8
        for (int kk = 0; kk < 32; ++kk) {
            float w0 = Ws[kk * 96 + j];
            float w1 = Ws[kk * 96 + j + 32];
            float w2 = Ws[kk * 96 + j + 64];
            float4 xa = *(const float4*)(xT + kk * 68 + ty * 8);
            float4 xb = *(const float4*)(xT + kk * 68 + ty * 8 + 4);
#define ROWFMA(r, xv)                                   \
            acc[r][0] = fmaf(xv, w0, acc[r][0]);        \
            acc[r][1] = fmaf(xv, w1, acc[r][1]);        \
            acc[r][2] = fmaf(xv, w2, acc[r][2]);
            ROWFMA(0, xa.x) ROWFMA(1, xa.y) ROWFMA(2, xa.z) ROWFMA(3, xa.w)
            ROWFMA(4, xb.x) ROWFMA(5, xb.y) ROWFMA(6, xb.z) ROWFMA(7, xb.w)
#undef ROWFMA
        }
    }
    #pragma unroll
    for (int r = 0; r < 8; ++r) {
        int v = v0 + ty * 8 + r;
        if (v < N_NODES) {
            S[(size_t)v * 96 + j]      = acc[r][0];
            S[(size_t)v * 96 + j + 32] = acc[r][1];
            S[(size_t)v * 96 + j + 64] = acc[r][2];
        }
    }
}

// Self GEMM, 16-row K-chunks (R9-proven; used by k_fusedC). LDS 10.75KB.
__device__ __forceinline__ void selfgemm16(int g, const float* __restrict__ X,
                                           const float* __restrict__ W96,
                                           const float* __restrict__ bias,
                                           float* __restrict__ S,
                                           float* __restrict__ Ws,   // [16*96]
                                           float* __restrict__ xT) { // [16*68]
    const int tid = threadIdx.x;
    const int j   = tid & 31;
    const int ty  = tid >> 5;
    const int v0  = g * 64;

    float acc[8][3];
    float b0 = bias[j], b1 = bias[j + 32], b2 = bias[j + 64];
    #pragma unroll
    for (int r = 0; r < 8; ++r) { acc[r][0] = b0; acc[r][1] = b1; acc[r][2] = b2; }

    const int sr = tid >> 2;
    const int sc = tid & 3;
    int sv = v0 + sr; if (sv >= N_NODES) sv = N_NODES - 1;

    for (int kc = 0; kc < 6; ++kc) {
        const float* W = W96 + kc * (16 * 96);
        const int kbase = kc * 16;
        __syncthreads();
        *(float4*)(Ws + tid * 4) = ld4(W + tid * 4);
        if (tid < 128)
            *(float4*)(Ws + (tid + 256) * 4) = ld4(W + (tid + 256) * 4);
        {
            float4 a = ld4(X + (size_t)sv * 96 + kbase + sc * 4);
            int k0 = sc * 4;
            xT[(k0 + 0) * 68 + sr] = a.x;
            xT[(k0 + 1) * 68 + sr] = a.y;
            xT[(k0 + 2) * 68 + sr] = a.z;
            xT[(k0 + 3) * 68 + sr] = a.w;
        }
        __syncthreads();
        #pragma unroll 8
        for (int kk = 0; kk < 16; ++kk) {
            float w0 = Ws[kk * 96 + j];
            float w1 = Ws[kk * 96 + j + 32];
            float w2 = Ws[kk * 96 + j + 64];
            float4 xa = *(const float4*)(xT + kk * 68 + ty * 8);
            float4 xb = *(const float4*)(xT + kk * 68 + ty * 8 + 4);
#define ROWFMA(r, xv)                                   \
            acc[r][0] = fmaf(xv, w0, acc[r][0]);        \
            acc[r][1] = fmaf(xv, w1, acc[r][1]);        \
            acc[r][2] = fmaf(xv, w2, acc[r][2]);
            ROWFMA(0, xa.x) ROWFMA(1, xa.y) ROWFMA(2, xa.z) ROWFMA(3, xa.w)
            ROWFMA(4, xb.x) ROWFMA(5, xb.y) ROWFMA(6, xb.z) ROWFMA(7, xb.w)
#undef ROWFMA
        }
    }
    #pragma unroll
    for (int r = 0; r < 8; ++r) {
        int v = v0 + ty * 8 + r;
        if (v < N_NODES) {
            S[(size_t)v * 96 + j]      = acc[r][0];
            S[(size_t)v * 96 + j + 32] = acc[r][1];
            S[(size_t)v * 96 + j + 64] = acc[r][2];
        }
    }
}

// ---------------- kernels ----------------

// A (R6-proven form): bucket build (even) || S1 = Features@W1r + b1 (odd)
__global__ __launch_bounds__(256) void k_fusedA(const int* __restrict__ src,
                                                const int* __restrict__ dst,
                                                int* __restrict__ degS,
                                                unsigned short* __restrict__ bucket,
                                                const float* __restrict__ X,
                                                const float* __restrict__ Wr,
                                                const float* __restrict__ bias,
                                                float* __restrict__ S) {
    __shared__ float Ws[32 * 96];
    __shared__ float xT[32 * 68];
    int b = blockIdx.x;
    if (b & 1) selfgemm32(b >> 1, X, Wr, bias, S, Ws, xT);
    else       bucket_role(b >> 1, src, dst, degS, bucket);
}

// pure aggregation layer 1 (R6-proven single-chunk form)
__global__ __launch_bounds__(256, 4) void k_aggr(const float* __restrict__ x,
                                                 const int* __restrict__ degS,
                                                 const unsigned short* __restrict__ bucket,
                                                 float* __restrict__ out) {
    aggr_role1(blockIdx.x, x, degS, bucket, out);
}

// C (R9-proven form): groups of 5 blocks: 2x selfgemm16(S2) + 3x 4-chunk aggr2.
__global__ __launch_bounds__(256, 4) void k_fusedC(const float* __restrict__ h1,
                                                   const int* __restrict__ degS,
                                                   const unsigned short* __restrict__ bucket,
                                                   float* __restrict__ aggrOut,
                                                   const float* __restrict__ Wr,
                                                   const float* __restrict__ bias,
                                                   float* __restrict__ S) {
    __shared__ float Ws[16 * 96];
    __shared__ float xT[16 * 68];
    int b = blockIdx.x;
    int g = b / 5, r = b - g * 5;
    if (r < 2) {
        int idx = g * 2 + r;                 // 0..781
        if (idx < NB_GEMM) selfgemm16(idx, h1, Wr, bias, S, Ws, xT);
    } else {
        int slot = g * 3 + (r - 2);          // 0..1172
        aggr_role4(slot, NSLOT_C, h1, degS, bucket, aggrOut);
    }
}

// Half GEMM: out = [RELU](P @ Wl + S). R4 192-thread static pipeline, 3 chunks.
template <int RELU>
__global__ __launch_bounds__(192) void k_gemmH(const float* __restrict__ P,
                                               const float* __restrict__ Wl,
                                               const float* __restrict__ S,
                                               float* __restrict__ out) {
    __shared__ float Ws[32 * 96];
    __shared__ float xT[32 * 68];
    const int tid = threadIdx.x;
    const int q   = tid % 24;
    const int rg  = tid / 24;
    const int v0  = blockIdx.x * 64;

    const int  row0 = tid >> 3,         qd0 = tid & 7;
    const int  row1 = (tid + 192) >> 3, qd1 = (tid + 192) & 7;
    const int  row2 = (tid + 384) >> 3, qd2 = (tid + 384) & 7;
    const bool has2 = (tid < 128);
    int sv0 = v0 + row0; if (sv0 >= N_NODES) sv0 = N_NODES - 1;
    int sv1 = v0 + row1; if (sv1 >= N_NODES) sv1 = N_NODES - 1;
    int sv2 = v0 + row2; if (sv2 >= N_NODES) sv2 = N_NODES - 1;

    float4 acc[8];
    #pragma unroll
    for (int r = 0; r < 8; ++r) acc[r] = make_float4(0.f, 0.f, 0.f, 0.f);

    float4 wreg0, wreg1, wreg2, wreg3;
    float4 xreg0, xreg1, xreg2;

    auto load_chunk = [&](int kc) {
        const float* W = Wl + kc * (32 * 96);
        const int kbase = kc * 32;
        wreg0 = *(const float4*)(W + (tid + 0 * 192) * 4);
        wreg1 = *(const float4*)(W + (tid + 1 * 192) * 4);
        wreg2 = *(const float4*)(W + (tid + 2 * 192) * 4);
        wreg3 = *(const float4*)(W + (tid + 3 * 192) * 4);
        xreg0 = *(const float4*)(P + (size_t)sv0 * 96 + kbase + qd0 * 4);
        xreg1 = *(const float4*)(P + (size_t)sv1 * 96 + kbase + qd1 * 4);
        if (has2) xreg2 = *(const float4*)(P + (size_t)sv2 * 96 + kbase + qd2 * 4);
    };
    auto store_chunk = [&]() {
        *(float4*)(Ws + (tid + 0 * 192) * 4) = wreg0;
        *(float4*)(Ws + (tid + 1 * 192) * 4) = wreg1;
        *(float4*)(Ws + (tid + 2 * 192) * 4) = wreg2;
        *(float4*)(Ws + (tid + 3 * 192) * 4) = wreg3;
        int k0 = qd0 * 4;
        xT[(k0 + 0) * 68 + row0] = xreg0.x;
        xT[(k0 + 1) * 68 + row0] = xreg0.y;
        xT[(k0 + 2) * 68 + row0] = xreg0.z;
        xT[(k0 + 3) * 68 + row0] = xreg0.w;
        int k1 = qd1 * 4;
        xT[(k1 + 0) * 68 + row1] = xreg1.x;
        xT[(k1 + 1) * 68 + row1] = xreg1.y;
        xT[(k1 + 2) * 68 + row1] = xreg1.z;
        xT[(k1 + 3) * 68 + row1] = xreg1.w;
        if (has2) {
            int k2 = qd2 * 4;
            xT[(k2 + 0) * 68 + row2] = xreg2.x;
            xT[(k2 + 1) * 68 + row2] = xreg2.y;
            xT[(k2 + 2) * 68 + row2] = xreg2.z;
            xT[(k2 + 3) * 68 + row2] = xreg2.w;
        }
    };

    load_chunk(0);
    for (int kc = 0; kc < 3; ++kc) {
        __syncthreads();
        store_chunk();
        if (kc < 2) load_chunk(kc + 1);
        __syncthreads();
        #pragma unroll 8
        for (int kk = 0; kk < 32; ++kk) {
            float4 w  = *(const float4*)(Ws + kk * 96 + q * 4);
            float4 xa = *(const float4*)(xT + kk * 68 + rg * 8);
            float4 xb = *(const float4*)(xT + kk * 68 + rg * 8 + 4);
            acc[0] = f4fma(xa.x, w, acc[0]);
            acc[1] = f4fma(xa.y, w, acc[1]);
            acc[2] = f4fma(xa.z, w, acc[2]);
            acc[3] = f4fma(xa.w, w, acc[3]);
            acc[4] = f4fma(xb.x, w, acc[4]);
            acc[5] = f4fma(xb.y, w, acc[5]);
            acc[6] = f4fma(xb.z, w, acc[6]);
            acc[7] = f4fma(xb.w, w, acc[7]);
        }
    }
    #pragma unroll
    for (int r = 0; r < 8; ++r) {
        int v = v0 + rg * 8 + r;
        if (v < N_NODES) {
            float4 s4 = *(const float4*)(S + (size_t)v * 96 + q * 4);
            float4 o = f4add(acc[r], s4);
            if (RELU) {
                o.x = fmaxf(o.x, 0.f); o.y = fmaxf(o.y, 0.f);
                o.z = fmaxf(o.z, 0.f); o.w = fmaxf(o.w, 0.f);
            }
            *(float4*)(out + (size_t)v * 96 + q * 4) = o;
        }
    }
}

// Edge scoring (R6-proven form): sigmoid(dot(h[E0], h[E1])), 8 lanes/edge,
// 2 edges/thread. R10 proved 4 edges/thread regresses (compiler serializes).
__global__ __launch_bounds__(256) void k_score(const float* __restrict__ h,
                                               const int* __restrict__ E,
                                               float* __restrict__ out) {
    int t = blockIdx.x * 256 + threadIdx.x;
    int e = t >> 3, sub = t & 7;
    if (e >= HALF_EVAL) return;
    int e2 = e + HALF_EVAL;
    int s0 = E[e];
    int d0 = E[N_EVAL + e];
    int s1 = E[e2];
    int d1 = E[N_EVAL + e2];
    const float* ps0 = h + (size_t)s0 * 96 + sub * 12;
    const float* pd0 = h + (size_t)d0 * 96 + sub * 12;
    const float* ps1 = h + (size_t)s1 * 96 + sub * 12;
    const float* pd1 = h + (size_t)d1 * 96 + sub * 12;
    float4 a0 = ld4(ps0 + 0), a1 = ld4(ps0 + 4), a2 = ld4(ps0 + 8);
    float4 b0 = ld4(pd0 + 0), b1 = ld4(pd0 + 4), b2 = ld4(pd0 + 8);
    float4 c0 = ld4(ps1 + 0), c1 = ld4(ps1 + 4), c2 = ld4(ps1 + 8);
    float4 g0 = ld4(pd1 + 0), g1 = ld4(pd1 + 4), g2 = ld4(pd1 + 8);
    float dot0 = a0.x * b0.x + a0.y * b0.y + a0.z * b0.z + a0.w * b0.w
               + a1.x * b1.x + a1.y * b1.y + a1.z * b1.z + a1.w * b1.w
               + a2.x * b2.x + a2.y * b2.y + a2.z * b2.z + a2.w * b2.w;
    float dot1 = c0.x * g0.x + c0.y * g0.y + c0.z * g0.z + c0.w * g0.w
               + c1.x * g1.x + c1.y * g1.y + c1.z * g1.z + c1.w * g1.w
               + c2.x * g2.x + c2.y * g2.y + c2.z * g2.z + c2.w * g2.w;
    dot0 += __shfl_xor(dot0, 1, 64);
    dot1 += __shfl_xor(dot1, 1, 64);
    dot0 += __shfl_xor(dot0, 2, 64);
    dot1 += __shfl_xor(dot1, 2, 64);
    dot0 += __shfl_xor(dot0, 4, 64);
    dot1 += __shfl_xor(dot1, 4, 64);
    if (sub == 0) {
        out[e]  = 1.f / (1.f + expf(-dot0));
        out[e2] = 1.f / (1.f + expf(-dot1));
    }
}

// ---------------- launch ----------------

extern "C" void kernel_launch(void* const* d_in, const int* in_sizes, int n_in,
                              void* d_out, int out_size, void* d_ws, size_t ws_size,
                              hipStream_t stream) {
    const float* Features = (const float*)d_in[0];
    const int*   A        = (const int*)d_in[1];   // [2, N_EDGES] int32
    const int*   E        = (const int*)d_in[2];   // [2, N_EVAL]
    const float* W1l = (const float*)d_in[3];
    const float* W1r = (const float*)d_in[4];
    const float* b1  = (const float*)d_in[5];
    const float* W2l = (const float*)d_in[6];
    const float* W2r = (const float*)d_in[7];
    const float* b2  = (const float*)d_in[8];
    float* out = (float*)d_out;

    char* p = (char*)d_ws;
    auto alloc = [&](size_t bytes) -> char* {
        char* q = p;
        p += (bytes + 255) & ~(size_t)255;
        return q;
    };
    int*   degS   = (int*)alloc((size_t)N_NODES * CSTRIDE * 4);   // 3.2 MB
    unsigned short* bucket =
        (unsigned short*)alloc((size_t)N_NODES * MAXDEG * 2);     // 6.4 MB
    float* bufA   = (float*)alloc((size_t)N_NODES * 96 * 4);      // aggr out / h2
    float* bufB   = (float*)alloc((size_t)N_NODES * 96 * 4);      // h1
    float* bufS   = (float*)alloc((size_t)N_NODES * 96 * 4);      // self term S1/S2

    const int* Asrc = A;
    const int* Adst = A + N_EDGES;

    hipMemsetAsync(degS, 0, (size_t)N_NODES * CSTRIDE * 4, stream);

    // bucket build || S1 = Features@W1r + b1  (independent, block-interleaved)
    k_fusedA<<<2 * NB_GEMM, 256, 0, stream>>>(Asrc, Adst, degS, bucket,
                                              Features, W1r, b1, bufS);
    // aggr1(Features) -> bufA  (single-chunk, R6-proven)
    k_aggr<<<NB_AGG, 256, 0, stream>>>(Features, degS, bucket, bufA);
    // h1 = relu(bufA@W1l + S1) -> bufB
    k_gemmH<1><<<NB_GEMM, 192, 0, stream>>>(bufA, W1l, bufS, bufB);
    // aggr2(h1) -> bufA || S2 = h1@W2r + b2 -> bufS  (R9-proven 5-block groups)
    k_fusedC<<<391 * 5, 256, 0, stream>>>(bufB, degS, bucket, bufA,
                                          W2r, b2, bufS);
    // h2 = bufA@W2l + S2 -> bufA
    k_gemmH<0><<<NB_GEMM, 192, 0, stream>>>(bufA, W2l, bufS, bufA);
    // score (2 edges/thread, R6-proven)
    k_score<<<(HALF_EVAL * 8 + 255) / 256, 256, 0, stream>>>(bufA, E, out);
}